// Round 6
// baseline (291.830 us; speedup 1.0000x reference)
//
#include <hip/hip_runtime.h>
#include <cmath>

#define B_SZ  1024
#define NORB  128
#define NUP   32
#define HID   4096
#define NCORR (NORB * NUP)   // 4096
#define K1    (4 * NORB)     // 512, one-hot GEMM K-dim

typedef short  bf16x8 __attribute__((ext_vector_type(8)));
typedef float  f32x4  __attribute__((ext_vector_type(4)));

__device__ __forceinline__ unsigned short f2bf_rne(float f) {
    unsigned int u = __float_as_uint(f);
    u += 0x7FFFu + ((u >> 16) & 1u);
    return (unsigned short)(u >> 16);
}

// ---------------------------------------------------------------------------
// k_packx: x [1024][128] int32 (codes 0..3) -> xp [1024][8] dwords, 2b/orbital.
// ---------------------------------------------------------------------------
__global__ __launch_bounds__(256) void k_packx(const int* __restrict__ x,
                                               unsigned int* __restrict__ xp) {
    int t = threadIdx.x;
    int row = blockIdx.x * 32 + (t >> 3);
    int d = t & 7;
    const int* src = x + row * NORB + d * 16;
    unsigned int dw = 0;
#pragma unroll
    for (int b = 0; b < 16; ++b) dw |= ((unsigned int)(src[b] & 3)) << (2 * b);
    xp[row * 8 + d] = dw;
}

// ---------------------------------------------------------------------------
// k_splitW: W [rows][4096] f32 -> hi/lo bf16 in MFMA B-FRAGMENT ORDER:
//   flat = ((nt*ktTot + kt)*64 + lane)*8 + j
//   nt=n>>4, kt=k>>5, lane=((k>>3)&3)*16 + (n&15), j=k&7.
// Used for W2 (ktTot=128) and W1 (ktTot=16). Tile 64k x 32n via LDS.
// ---------------------------------------------------------------------------
__global__ __launch_bounds__(256) void k_splitW(const float* __restrict__ W,
                                                unsigned short* __restrict__ Bph,
                                                unsigned short* __restrict__ Bpl,
                                                int ktTot) {
    __shared__ float tile[64][33];
    int n0 = blockIdx.x * 32, k0 = blockIdx.y * 64;
    int t = threadIdx.x;
    int nl = t & 31, kg = t >> 5;
#pragma unroll
    for (int i = 0; i < 8; ++i) {
        int kl = kg + i * 8;
        tile[kl][nl] = W[(size_t)(k0 + kl) * 4096 + n0 + nl];
    }
    __syncthreads();

    int nt = (n0 + nl) >> 4;
    int kt = (k0 >> 5) + (kg >> 2);
    int lane_o = (kg & 3) * 16 + (nl & 15);
    size_t o = (((size_t)nt * ktTot + kt) * 64 + lane_o) * 8;

    unsigned short hi8[8], lo8[8];
#pragma unroll
    for (int j = 0; j < 8; ++j) {
        float v = tile[kg * 8 + j][nl];
        unsigned short hi = f2bf_rne(v);
        float fhi = __uint_as_float((unsigned int)hi << 16);
        hi8[j] = hi;
        lo8[j] = f2bf_rne(v - fhi);
    }
    *(bf16x8*)(Bph + o) = *(bf16x8*)hi8;
    *(bf16x8*)(Bpl + o) = *(bf16x8*)lo8;
}

// ---------------------------------------------------------------------------
// k_hidden2: h = relu(one_hot(x) @ (W1hi + W1lo) + b1).
// Output: h in A-FRAGMENT-PACKED split-bf16:
//   flat = ((mt*128 + kt)*64 + lane)*8 + j
//   mt=m>>4, kt=n>>5 (n = hidden idx = k of GEMM2), lane=((n>>3)&3)*16+(m&15).
// Epilogue transposes D-layout -> A-frag layout through LDS (f32).
// ---------------------------------------------------------------------------
__global__ __launch_bounds__(256) void k_hidden2(const unsigned int* __restrict__ xp,
                                                 const unsigned short* __restrict__ Bph,
                                                 const unsigned short* __restrict__ Bpl,
                                                 const float* __restrict__ b1,
                                                 unsigned short* __restrict__ h_hi,
                                                 unsigned short* __restrict__ h_lo) {
    __shared__ unsigned int sxp[64][8];   // packed codes for the m-tile (2 KB)
    __shared__ float Ht[64][132];         // 64m x 128n f32 tile (33.8 KB)

    int n0 = blockIdx.x * 128;
    int m0 = blockIdx.y * 64;
    int t = threadIdx.x;
    int w = t >> 6, lane = t & 63;
    int lm = lane & 15, kq = lane >> 4;
    int wn = w * 32;

#pragma unroll
    for (int i = 0; i < 2; ++i) {
        int idx = t + 256 * i;
        sxp[idx >> 3][idx & 7] = xp[(m0 + (idx >> 3)) * 8 + (idx & 7)];
    }
    __syncthreads();

    size_t nt0 = (size_t)((n0 + wn) >> 4);
    const unsigned short* bph = Bph + nt0 * (16 * 512) + (size_t)lane * 8;
    const unsigned short* bpl = Bpl + nt0 * (16 * 512) + (size_t)lane * 8;

    f32x4 acc[4][2] = {};

    bf16x8 nbh0 = *(const bf16x8*)(bph);
    bf16x8 nbh1 = *(const bf16x8*)(bph + 16 * 512);
    bf16x8 nbl0 = *(const bf16x8*)(bpl);
    bf16x8 nbl1 = *(const bf16x8*)(bpl + 16 * 512);

    for (int kt = 0; kt < 16; ++kt) {
        bf16x8 bh0 = nbh0, bh1 = nbh1, bl0 = nbl0, bl1 = nbl1;
        if (kt + 1 < 16) {
            nbh0 = *(const bf16x8*)(bph + (kt + 1) * 512);
            nbh1 = *(const bf16x8*)(bph + 16 * 512 + (kt + 1) * 512);
            nbl0 = *(const bf16x8*)(bpl + (kt + 1) * 512);
            nbl1 = *(const bf16x8*)(bpl + 16 * 512 + (kt + 1) * 512);
        }

        int i0 = kt * 8 + kq * 2;
        int dwIdx = i0 >> 4;
        int sh = (i0 & 15) * 2;
        bf16x8 af[4];
#pragma unroll
        for (int fm = 0; fm < 4; ++fm) {
            unsigned int dw = sxp[fm * 16 + lm][dwIdx];
            unsigned int c01 = (dw >> sh) & 0xFu;
            union { bf16x8 v; unsigned long long u[2]; } a;
            a.u[0] = 0x3F80ULL << ((c01 & 3u) * 16);
            a.u[1] = 0x3F80ULL << ((c01 >> 2) * 16);
            af[fm] = a.v;
        }

#pragma unroll
        for (int fm = 0; fm < 4; ++fm) {
            acc[fm][0] = __builtin_amdgcn_mfma_f32_16x16x32_bf16(af[fm], bh0, acc[fm][0], 0, 0, 0);
            acc[fm][0] = __builtin_amdgcn_mfma_f32_16x16x32_bf16(af[fm], bl0, acc[fm][0], 0, 0, 0);
            acc[fm][1] = __builtin_amdgcn_mfma_f32_16x16x32_bf16(af[fm], bh1, acc[fm][1], 0, 0, 0);
            acc[fm][1] = __builtin_amdgcn_mfma_f32_16x16x32_bf16(af[fm], bl1, acc[fm][1], 0, 0, 0);
        }
    }

    // ---- epilogue: bias+relu into LDS (D-layout), read back in A-frag order
#pragma unroll
    for (int fm = 0; fm < 4; ++fm)
#pragma unroll
        for (int fn = 0; fn < 2; ++fn) {
            int n = wn + fn * 16 + lm;
            float bv = b1[n0 + n];
#pragma unroll
            for (int r = 0; r < 4; ++r)
                Ht[fm * 16 + kq * 4 + r][n] = fmaxf(acc[fm][fn][r] + bv, 0.f);
        }
    __syncthreads();

    size_t mt0 = (size_t)(m0 >> 4), kt0 = (size_t)(n0 >> 5);
#pragma unroll
    for (int fi = 0; fi < 4; ++fi) {
        int f = w * 4 + fi;                 // 0..15
        int mt = f >> 2, ktn = f & 3;
        int m = mt * 16 + lm;
        int kn = ktn * 32 + kq * 8;
        float4 v0 = *(const float4*)&Ht[m][kn];
        float4 v1 = *(const float4*)&Ht[m][kn + 4];
        float vv[8] = {v0.x, v0.y, v0.z, v0.w, v1.x, v1.y, v1.z, v1.w};
        unsigned short hi8[8], lo8[8];
#pragma unroll
        for (int j = 0; j < 8; ++j) {
            unsigned short hi = f2bf_rne(vv[j]);
            float fhi = __uint_as_float((unsigned int)hi << 16);
            hi8[j] = hi;
            lo8[j] = f2bf_rne(vv[j] - fhi);
        }
        size_t o = (((mt0 + mt) * 128 + (kt0 + ktn)) * 64 + lane) * 8;
        *(bf16x8*)(h_hi + o) = *(bf16x8*)hi8;
        *(bf16x8*)(h_lo + o) = *(bf16x8*)lo8;
    }
}

// ---------------------------------------------------------------------------
// f32 fallback hidden (small-workspace path)
// ---------------------------------------------------------------------------
__global__ __launch_bounds__(256) void k_hidden_f32(const int* __restrict__ x,
                                                    const float* __restrict__ W1,
                                                    const float* __restrict__ b1,
                                                    float* __restrict__ h) {
    int b = blockIdx.x, tid = threadIdx.x;
    __shared__ int sx[NORB];
    if (tid < NORB) sx[tid] = x[b * NORB + tid];
    __syncthreads();
    float acc[16];
#pragma unroll
    for (int u = 0; u < 16; ++u) acc[u] = b1[tid + 256 * u];
    for (int i = 0; i < NORB; ++i) {
        const float* row = W1 + (size_t)(4 * i + sx[i]) * HID;
#pragma unroll
        for (int u = 0; u < 16; ++u) acc[u] += row[tid + 256 * u];
    }
    float* hb = h + (size_t)b * HID;
#pragma unroll
    for (int u = 0; u < 16; ++u) hb[tid + 256 * u] = fmaxf(acc[u], 0.f);
}

// ---------------------------------------------------------------------------
// k_gemm4: corr = (h_hi+h_lo)@W2_hi + h_hi@W2_lo + b2, bf16 MFMA, f32 acc.
// BOTH operands fragment-packed in global memory. NO LDS, NO barriers.
// Per kt: 12 coalesced 1KB loads (prefetched 1 iter ahead) + 24 MFMA.
// Tile 64m x 128n, 4 waves each 64m x 32n; A-frags shared via L1.
// ---------------------------------------------------------------------------
__global__ __launch_bounds__(256) void k_gemm4(const unsigned short* __restrict__ Ahp,
                                               const unsigned short* __restrict__ Alp,
                                               const unsigned short* __restrict__ Bph,
                                               const unsigned short* __restrict__ Bpl,
                                               const float* __restrict__ bias,
                                               float* __restrict__ C) {
    int n0 = blockIdx.x * 128;
    int m0 = blockIdx.y * 64;
    int t = threadIdx.x;
    int w = t >> 6, lane = t & 63;
    int lm = lane & 15, kq = lane >> 4;
    int wn = w * 32;

    size_t mt0 = (size_t)(m0 >> 4);
    size_t nt0 = (size_t)((n0 + wn) >> 4);
    // frag (mt0+i, kt) at + (i*128 + kt)*512 elems from these bases:
    const unsigned short* ah = Ahp + (mt0 * 128 * 64 + lane) * 8;
    const unsigned short* al = Alp + (mt0 * 128 * 64 + lane) * 8;
    const unsigned short* bh = Bph + (nt0 * 128 * 64 + lane) * 8;
    const unsigned short* bl = Bpl + (nt0 * 128 * 64 + lane) * 8;

    f32x4 acc[4][2] = {};
    bf16x8 cah[4], cal[4], cbh[2], cbl[2];

    // prologue: kt = 0
#pragma unroll
    for (int i = 0; i < 4; ++i) {
        cah[i] = *(const bf16x8*)(ah + (size_t)i * 65536);
        cal[i] = *(const bf16x8*)(al + (size_t)i * 65536);
    }
#pragma unroll
    for (int i = 0; i < 2; ++i) {
        cbh[i] = *(const bf16x8*)(bh + (size_t)i * 65536);
        cbl[i] = *(const bf16x8*)(bl + (size_t)i * 65536);
    }

    for (int kt = 0; kt < 128; ++kt) {
        int ktn = (kt + 1 < 128) ? kt + 1 : 127;   // uniform control flow
        bf16x8 nah[4], nal[4], nbh[2], nbl[2];
#pragma unroll
        for (int i = 0; i < 4; ++i) {
            nah[i] = *(const bf16x8*)(ah + (size_t)i * 65536 + (size_t)ktn * 512);
            nal[i] = *(const bf16x8*)(al + (size_t)i * 65536 + (size_t)ktn * 512);
        }
#pragma unroll
        for (int i = 0; i < 2; ++i) {
            nbh[i] = *(const bf16x8*)(bh + (size_t)i * 65536 + (size_t)ktn * 512);
            nbl[i] = *(const bf16x8*)(bl + (size_t)i * 65536 + (size_t)ktn * 512);
        }

#pragma unroll
        for (int fm = 0; fm < 4; ++fm) {
            acc[fm][0] = __builtin_amdgcn_mfma_f32_16x16x32_bf16(cah[fm], cbh[0], acc[fm][0], 0, 0, 0);
            acc[fm][0] = __builtin_amdgcn_mfma_f32_16x16x32_bf16(cal[fm], cbh[0], acc[fm][0], 0, 0, 0);
            acc[fm][0] = __builtin_amdgcn_mfma_f32_16x16x32_bf16(cah[fm], cbl[0], acc[fm][0], 0, 0, 0);
            acc[fm][1] = __builtin_amdgcn_mfma_f32_16x16x32_bf16(cah[fm], cbh[1], acc[fm][1], 0, 0, 0);
            acc[fm][1] = __builtin_amdgcn_mfma_f32_16x16x32_bf16(cal[fm], cbh[1], acc[fm][1], 0, 0, 0);
            acc[fm][1] = __builtin_amdgcn_mfma_f32_16x16x32_bf16(cah[fm], cbl[1], acc[fm][1], 0, 0, 0);
        }

#pragma unroll
        for (int i = 0; i < 4; ++i) { cah[i] = nah[i]; cal[i] = nal[i]; }
#pragma unroll
        for (int i = 0; i < 2; ++i) { cbh[i] = nbh[i]; cbl[i] = nbl[i]; }
    }

    // epilogue: bias + store
#pragma unroll
    for (int fm = 0; fm < 4; ++fm)
#pragma unroll
        for (int fn = 0; fn < 2; ++fn) {
            int n = n0 + wn + fn * 16 + lm;
            float bv = bias[n];
#pragma unroll
            for (int r = 0; r < 4; ++r) {
                int m = m0 + fm * 16 + kq * 4 + r;
                C[(size_t)m * NCORR + n] = acc[fm][fn][r] + bv;
            }
        }
}

// ---------------------------------------------------------------------------
// f32 fallback GEMM (round-2 kernel, unchanged)
// ---------------------------------------------------------------------------
#define BM 64
#define BN 64
#define BK 32
__global__ __launch_bounds__(256) void k_gemm(const float* __restrict__ A,
                                              const float* __restrict__ Bm,
                                              const float* __restrict__ bias,
                                              float* __restrict__ C) {
    __shared__ float As[BK][68];
    __shared__ float Bs[BK][BN];
    int n0 = blockIdx.x * BN, m0 = blockIdx.y * BM;
    int tid = threadIdx.x;
    int tm = tid >> 4, tn = tid & 15;
    int am = tid >> 3, ak = (tid & 7) * 4;
    int bk = tid >> 4, bn = (tid & 15) * 4;
    float acc[4][4] = {};
    for (int k0 = 0; k0 < HID; k0 += BK) {
#pragma unroll
        for (int s = 0; s < 2; ++s) {
            int m = am + 32 * s;
            float4 v = *(const float4*)(A + (size_t)(m0 + m) * HID + k0 + ak);
            As[ak + 0][m] = v.x; As[ak + 1][m] = v.y;
            As[ak + 2][m] = v.z; As[ak + 3][m] = v.w;
        }
#pragma unroll
        for (int s = 0; s < 2; ++s) {
            int k = bk + 16 * s;
            float4 v = *(const float4*)(Bm + (size_t)(k0 + k) * NCORR + n0 + bn);
            *(float4*)&Bs[k][bn] = v;
        }
        __syncthreads();
#pragma unroll
        for (int kk = 0; kk < BK; ++kk) {
            float4 a = *(const float4*)&As[kk][tm * 4];
            float4 bv = *(const float4*)&Bs[kk][tn * 4];
            float av[4] = {a.x, a.y, a.z, a.w};
            float bb[4] = {bv.x, bv.y, bv.z, bv.w};
#pragma unroll
            for (int i = 0; i < 4; ++i)
#pragma unroll
                for (int j = 0; j < 4; ++j) acc[i][j] += av[i] * bb[j];
        }
        __syncthreads();
    }
#pragma unroll
    for (int i = 0; i < 4; ++i) {
        int m = m0 + tm * 4 + i;
        float4 o;
        o.x = acc[i][0] + bias[n0 + tn * 4 + 0];
        o.y = acc[i][1] + bias[n0 + tn * 4 + 1];
        o.z = acc[i][2] + bias[n0 + tn * 4 + 2];
        o.w = acc[i][3] + bias[n0 + tn * 4 + 3];
        *(float4*)(C + (size_t)m * NCORR + n0 + tn * 4) = o;
    }
}

// ---------------------------------------------------------------------------
// Kernel C: gather + 32x32 LU (partial pivoting) per spin, planar complex out.
// ---------------------------------------------------------------------------
__global__ __launch_bounds__(128) void k_det(const int* __restrict__ x,
                                             const float* __restrict__ orbitals,
                                             const float* __restrict__ corr,
                                             float* __restrict__ out,
                                             int imag_off) {
    int b = blockIdx.x, tid = threadIdx.x;
    __shared__ int sx[NORB];
    __shared__ int yup[NUP], ydn[NUP];
    __shared__ float M[2][NUP][NUP + 1];
    __shared__ float rlog[2];
    __shared__ int rneg[2];

    sx[tid] = x[b * NORB + tid];
    __syncthreads();

    int occ = sx[tid];
    if (occ & 1) {
        int r = 0;
        for (int i = 0; i < tid; ++i) r += sx[i] & 1;
        yup[r] = tid;
    }
    if (occ & 2) {
        int r = 0;
        for (int i = 0; i < tid; ++i) r += (sx[i] >> 1) & 1;
        ydn[r] = tid;
    }
    __syncthreads();

    const float* cb = corr + (size_t)b * NCORR;
    for (int idx = tid; idx < 2 * NUP * NUP; idx += 128) {
        int s = idx >> 10;
        int i = (idx >> 5) & 31;
        int j = idx & 31;
        int r = s ? ydn[i] : yup[i];
        M[s][i][j] = orbitals[r * NUP + j] + cb[r * NUP + j];
    }
    __syncthreads();

    int wv = tid >> 6, lane = tid & 63;
    float (*Mm)[NUP + 1] = M[wv];
    float logdet = 0.f;
    int neg = 0;

    for (int k = 0; k < NUP; ++k) {
        float v = (lane >= k && lane < NUP) ? fabsf(Mm[lane][k]) : -1.f;
        int pi = lane;
#pragma unroll
        for (int off = 32; off > 0; off >>= 1) {
            float v2 = __shfl_down(v, off);
            int p2 = __shfl_down(pi, off);
            if (v2 > v) { v = v2; pi = p2; }
        }
        int p = __shfl(pi, 0);

        if (p != k) {
            if (lane < NUP) {
                float t1 = Mm[k][lane];
                Mm[k][lane] = Mm[p][lane];
                Mm[p][lane] = t1;
            }
            neg ^= 1;
        }
        __syncthreads();

        float pv = Mm[k][k];
        logdet += logf(fabsf(pv));
        if (pv < 0.f) neg ^= 1;

        int row = k + 1 + (lane & 31);
        int half = lane >> 5;
        if (row < NUP) {
            float f = Mm[row][k] / pv;
            for (int j = k + 1 + half; j < NUP; j += 2)
                Mm[row][j] -= f * Mm[k][j];
        }
        __syncthreads();
    }

    if (lane == 0) { rlog[wv] = logdet; rneg[wv] = neg; }
    __syncthreads();
    if (tid == 0) {
        out[b] = rlog[0] + rlog[1];
        if (imag_off > 0)
            out[imag_off + b] =
                (rneg[0] ^ rneg[1]) ? 3.14159265358979323846f : 0.f;
    }
}

// ---------------------------------------------------------------------------
extern "C" void kernel_launch(void* const* d_in, const int* in_sizes, int n_in,
                              void* d_out, int out_size, void* d_ws, size_t ws_size,
                              hipStream_t stream) {
    const int*   x        = (const int*)d_in[0];
    const float* orbitals = (const float*)d_in[1];
    const float* W1       = (const float*)d_in[2];
    const float* b1       = (const float*)d_in[3];
    const float* W2       = (const float*)d_in[4];
    const float* b2       = (const float*)d_in[5];
    float* out = (float*)d_out;
    int imag_off = (out_size == 2 * B_SZ) ? B_SZ : 0;

    const size_t need = (size_t)96 * 1024 * 1024;
    if (ws_size >= need) {
        unsigned short* h_hi = (unsigned short*)d_ws;                    //  8 MB (A-frag packed)
        unsigned short* h_lo = h_hi + (size_t)B_SZ * HID;                //  8 MB
        unsigned short* Bph  = h_lo + (size_t)B_SZ * HID;                // 32 MB (B-frag packed)
        unsigned short* Bpl  = Bph + (size_t)HID * NCORR;                // 32 MB
        float*          corr = (float*)(Bpl + (size_t)HID * NCORR);     // 16 MB

        // W1-pack + packed-x live INSIDE the corr buffer (consumed by
        // k_hidden2 before k_gemm4 writes corr).
        unsigned short* W1ph = (unsigned short*)corr;                    // 4 MB
        unsigned short* W1pl = W1ph + (size_t)K1 * HID;                  // 4 MB
        unsigned int*   xp   = (unsigned int*)(W1pl + (size_t)K1 * HID); // 32 KB

        k_packx<<<B_SZ / 32, 256, 0, stream>>>(x, xp);
        k_splitW<<<dim3(HID / 32, K1 / 64), 256, 0, stream>>>(W1, W1ph, W1pl, 16);
        k_splitW<<<dim3(NCORR / 32, HID / 64), 256, 0, stream>>>(W2, Bph, Bpl, 128);

        k_hidden2<<<dim3(HID / 128, B_SZ / 64), 256, 0, stream>>>(xp, W1ph, W1pl, b1, h_hi, h_lo);

        dim3 g2(NCORR / 128, B_SZ / 64);    // 32 x 16 = 512 blocks
        k_gemm4<<<g2, 256, 0, stream>>>(h_hi, h_lo, Bph, Bpl, b2, corr);
        k_det<<<B_SZ, 128, 0, stream>>>(x, orbitals, corr, out, imag_off);
    } else {
        float* h    = (float*)d_ws;
        float* corr = h + (size_t)B_SZ * HID;
        k_hidden_f32<<<B_SZ, 256, 0, stream>>>(x, W1, b1, h);
        dim3 g2(NCORR / BN, B_SZ / BM);
        k_gemm<<<g2, 256, 0, stream>>>(h, W2, b2, corr);
        k_det<<<B_SZ, 128, 0, stream>>>(x, orbitals, corr, out, imag_off);
    }
}